// Round 5
// baseline (299.030 us; speedup 1.0000x reference)
//
#include <hip/hip_runtime.h>

// QuantizedBottleneck via i8 MFMA implicit GEMM. Exact integer math.
//   prep  : pack MFMA A-fragments (w1/w2/w3 -> i8) + wsum1 into d_ws
//   pack  : x int32 [b][ch][px] -> xq i8 [b][px][ch] = (x-128), LDS transpose
//   conv1 : 1x1 256->64 + bn1 -> t1 [n][64] i8. B-frags read DIRECTLY from xq
//           (xq row layout == MFMA B-frag layout). No LDS, no barriers.
//   conv23: fused 3x3 64->64 pad1 + bn2 -> LDS, then 1x1 64->256 + bn3 +
//           residual add -> out int32. Residual from xq (16 dwords/thread).
// Requant uses the exact single-shift identity:
//   ((p+nudge)>>31 + 2^(sh-1))>>sh == (p + nudge + 2^(30+sh)) >> (31+sh)
// xq holds x-128; conv1 corrects acc by (128-zin)*wsum; residual uses
// sx + (128 - az0) == x - az0.
// MFMA 16x16x64_i8: A[m=lane&15][k=(lane>>4)*16+j], B[k][n=lane&15],
// C/D: col=lane&15, row=(lane>>4)*4+reg.

typedef int v4i __attribute__((ext_vector_type(4)));

#define BATCH 32
#define CIN 256
#define CMID 64
#define HW 3136
#define W56 56

#define WP_BYTES ((size_t)68 * 64 * 16)
#define WSUM_BYTES ((size_t)64 * 4)
#define T1_BYTES ((size_t)BATCH * HW * CMID)

__device__ __forceinline__ int rq_apply(int acc, int m0, long long cp, long long cn,
                                        int shm1, int zo) {
    long long prod = (long long)acc * m0;
    prod += (prod >= 0) ? cp : cn;
    int hi = (int)((unsigned long long)prod >> 32);
    int v = (hi >> shm1) + zo;
    return v < 0 ? 0 : (v > 255 ? 255 : v);
}

__device__ __forceinline__ int ms_apply(int xin, int m0, long long cp, long long cn,
                                        int shm1) {
    long long prod = (long long)xin * m0;
    prod += (prod >= 0) ? cp : cn;
    return ((int)((unsigned long long)prod >> 32)) >> shm1;
}

// gather byte0 of four ints -> one dword (3 x v_perm_b32)
__device__ __forceinline__ unsigned int pk4x(int a0, int a1, int a2, int a3) {
    unsigned p01 = __builtin_amdgcn_perm((unsigned)a1, (unsigned)a0, 0x00000400u);
    unsigned p23 = __builtin_amdgcn_perm((unsigned)a3, (unsigned)a2, 0x04000000u);
    return __builtin_amdgcn_perm(p23, p01, 0x07060100u);
}

__device__ __forceinline__ v4i pack16f(const float* src, int stride) {
    v4i r;
#pragma unroll
    for (int d = 0; d < 4; ++d) {
        unsigned int u = 0;
#pragma unroll
        for (int by = 0; by < 4; ++by) {
            int v = (int)src[(d * 4 + by) * stride];
            u |= ((unsigned int)(v & 255)) << (8 * by);
        }
        r[d] = (int)u;
    }
    return r;
}

// -------- prep: fragsets w1 [0,16), w2 [16,52), w3 [52,68); block 17: wsum1 --
__global__ __launch_bounds__(256) void k_prep(
    const float* __restrict__ w1, const float* __restrict__ w2,
    const float* __restrict__ w3, v4i* __restrict__ wp, int* __restrict__ wsum)
{
    if (blockIdx.x < 17) {
        int id = blockIdx.x * 256 + threadIdx.x;
        int fid = id >> 6, lane = id & 63;
        int col = lane & 15, ci0 = (lane >> 4) * 16;
        const float* src;
        int stride;
        if (fid < 16) {
            int wv = fid >> 2, ks = fid & 3;
            src = w1 + (size_t)(wv * 16 + col) * 256 + ks * 64 + ci0;
            stride = 1;
        } else if (fid < 52) {
            int i = fid - 16, wv = i / 9, t = i - wv * 9;
            src = w2 + ((size_t)(wv * 16 + col) * 64 + ci0) * 9 + t;
            stride = 9;
        } else {
            int s = fid - 52;
            src = w3 + (size_t)(s * 16 + col) * 64 + ci0;
            stride = 1;
        }
        wp[fid * 64 + lane] = pack16f(src, stride);
    } else {
        // wsum1[co] = sum_ci w1[co][ci]  (4 threads per channel)
        int ch = threadIdx.x >> 2, t4 = threadIdx.x & 3;
        int s = 0;
        for (int i = 0; i < 64; ++i) s += (int)w1[(size_t)ch * 256 + t4 * 64 + i];
        s += __shfl_xor(s, 1);
        s += __shfl_xor(s, 2);
        if (t4 == 0) wsum[ch] = s;
    }
}

// -------- pack: x [b][256][3136] i32 -> xq [b][3136][256] i8 (x-128) --------
// grid (49, 32): 64-px x 256-ch tile per block. LDS transpose, 264B rows.
__global__ __launch_bounds__(256) void k_pack(
    const int* __restrict__ x, unsigned char* __restrict__ xq)
{
    __shared__ unsigned int lds[64 * 66];          // 264 B rows: 2-way max
    const int tid = threadIdx.x;
    const int b = blockIdx.y;
    const int px0 = blockIdx.x * 64;
    const int px = tid & 63, cb = (tid >> 6) * 64;
    const int* xb = x + (size_t)b * CIN * HW + px0 + px;
#pragma unroll
    for (int i = 0; i < 16; ++i) {
        int ch = cb + i * 4;
        int v0 = xb[(size_t)(ch + 0) * HW];
        int v1 = xb[(size_t)(ch + 1) * HW];
        int v2 = xb[(size_t)(ch + 2) * HW];
        int v3 = xb[(size_t)(ch + 3) * HW];
        lds[px * 66 + (ch >> 2)] = pk4x(v0, v1, v2, v3) ^ 0x80808080u;
    }
    __syncthreads();
    unsigned char* xqb = xq + ((size_t)b * HW + px0) * 256;
#pragma unroll
    for (int i = 0; i < 4; ++i) {
        int flat = tid + i * 256;
        int row = flat >> 4, off = (flat & 15) * 4;   // dword offset in row
        v4i o;
        o[0] = (int)lds[row * 66 + off + 0];
        o[1] = (int)lds[row * 66 + off + 1];
        o[2] = (int)lds[row * 66 + off + 2];
        o[3] = (int)lds[row * 66 + off + 3];
        *(v4i*)(xqb + (size_t)row * 256 + off * 4) = o;
    }
}

// -------- conv1: 1x1 256->64 + bn1 -> t1. grid (28, 32), 112-px tiles -------
// B-fragments load directly from xq (row layout == frag layout). No LDS,
// no barriers: 28 independent dwordx4 loads/wave, latency hidden by unroll.
__global__ __launch_bounds__(256, 2) void k_conv1(
    const unsigned char* __restrict__ xq, const v4i* __restrict__ wp1,
    const int* __restrict__ wsum1,
    const float* __restrict__ bn_w, const float* __restrict__ bn_b,
    const int* __restrict__ conv_zin, const int* __restrict__ conv_m0,
    const int* __restrict__ conv_shift, const int* __restrict__ conv_zout,
    const int* __restrict__ bn_m0, const int* __restrict__ bn_shift,
    const int* __restrict__ bn_zout, signed char* __restrict__ t1)
{
    const int tid = threadIdx.x, lane = tid & 63, wv = tid >> 6;
    const int col = lane & 15, koff = lane >> 4;
    const int b = blockIdx.y;
    const int hw0 = blockIdx.x * 112;
    const int co0 = wv * 16;

    v4i a[4];
#pragma unroll
    for (int ks = 0; ks < 4; ++ks) a[ks] = wp1[(wv * 4 + ks) * 64 + lane];

    const unsigned char* xqb = xq + ((size_t)b * HW + hw0) * 256 + koff * 16;

    v4i acc[7];
#pragma unroll
    for (int i = 0; i < 7; ++i) acc[i] = (v4i){0, 0, 0, 0};

#pragma unroll
    for (int ks = 0; ks < 4; ++ks) {
        v4i bf[7];
#pragma unroll
        for (int nt = 0; nt < 7; ++nt)
            bf[nt] = *(const v4i*)(xqb + (size_t)(nt * 16 + col) * 256 + ks * 64);
#pragma unroll
        for (int nt = 0; nt < 7; ++nt)
            acc[nt] = __builtin_amdgcn_mfma_i32_16x16x64_i8(a[ks], bf[nt], acc[nt], 0, 0, 0);
    }

    const int zin = conv_zin[0];
    const int corr0 = 128 - zin;                   // acc was computed vs x-128
    const int cm0 = conv_m0[0], csh = conv_shift[0], czo = conv_zout[0];
    const int bm0 = bn_m0[0], bsh = bn_shift[0], bzo = bn_zout[0];
    const int zin2 = conv_zin[1];
    const long long cbv = 1LL << (30 + csh);
    const long long ccp = cbv + (1LL << 30), ccn = cbv + 1 - (1LL << 30);
    const int cshm1 = csh - 1;
    const long long bbv = 1LL << (30 + bsh);
    const long long bcp = bbv + (1LL << 30), bcn = bbv + 1 - (1LL << 30);
    const int bshm1 = bsh - 1;
    const int rowb = koff * 4;
    int bw[4], bbx[4], ws[4];
#pragma unroll
    for (int r = 0; r < 4; ++r) {
        bw[r] = (int)bn_w[co0 + rowb + r];
        bbx[r] = (int)bn_b[co0 + rowb + r] - czo * bw[r];
        ws[r] = wsum1[co0 + rowb + r];
    }
#pragma unroll
    for (int nt = 0; nt < 7; ++nt) {
        int n = b * HW + hw0 + nt * 16 + col;
        int e[4];
#pragma unroll
        for (int r = 0; r < 4; ++r) {
            int av = acc[nt][r] + corr0 * ws[r];
            int qv = rq_apply(av, cm0, ccp, ccn, cshm1, czo);
            int a2 = qv * bw[r] + bbx[r];
            int q2 = rq_apply(a2, bm0, bcp, bcn, bshm1, bzo);
            e[r] = q2 - zin2;
        }
        *(unsigned*)(t1 + (size_t)n * 64 + co0 + rowb) = pk4x(e[0], e[1], e[2], e[3]);
    }
}

// -------- conv23: fused 3x3+bn2 (-> LDS) then 1x1 64->256 + bn3 + residual --
// grid (56, 32): 1 output row (64 px padded, 56 valid) x batch.
// Phase A: conv2 over 3 halo rows in sm -> t2s LDS (B-frag layout).
//          Residual xq dwords (all 4 steps) prefetched under phase-A epilogue.
// Phase B: bf[4] read once from t2s; 4 register-only MFMA+epilogue steps.
__global__ __launch_bounds__(256, 4) void k_conv23(
    const signed char* __restrict__ t1, const v4i* __restrict__ wp2,
    const v4i* __restrict__ wp3,
    const float* __restrict__ bn2_w, const float* __restrict__ bn2_b,
    const float* __restrict__ bn3_w, const float* __restrict__ bn3_b,
    const unsigned char* __restrict__ xq,
    const int* __restrict__ conv_zin, const int* __restrict__ conv_m0,
    const int* __restrict__ conv_shift, const int* __restrict__ conv_zout,
    const int* __restrict__ bn_m0, const int* __restrict__ bn_shift,
    const int* __restrict__ bn_zout,
    const int* __restrict__ add_z, const int* __restrict__ add_m0,
    const int* __restrict__ add_shift, const int* __restrict__ add_zout,
    int* __restrict__ out)
{
    __shared__ v4i sm[840];                       // 3 rows x 56 px x 80 B
    __shared__ v4i t2s[320];                      // 64 px x 80 B
    const int tid = threadIdx.x, lane = tid & 63, wv = tid >> 6;
    const int col = lane & 15, koff = lane >> 4;
    const int b = blockIdx.y;
    const int r0 = blockIdx.x;
    const int co0 = wv * 16, rowb = koff * 4;

    v4i a[9];
#pragma unroll
    for (int t = 0; t < 9; ++t) a[t] = wp2[(wv * 9 + t) * 64 + lane];
    v4i a3x[4];
#pragma unroll
    for (int s = 0; s < 4; ++s) a3x[s] = wp3[(wv * 4 + s) * 64 + lane];

    const v4i* t1v = (const v4i*)t1;
#pragma unroll
    for (int k = 0; k < 3; ++k) {
        int idx = tid + k * 256;
        if (idx < 672) {                          // 168 px x 4 parts
            int pixl = idx >> 2, part = idx & 3;
            int lrow = pixl / W56, gw = pixl - lrow * W56;
            int grow = r0 - 1 + lrow;
            v4i v = (v4i){0, 0, 0, 0};
            if ((unsigned)grow < 56u)
                v = t1v[((size_t)b * HW + grow * W56 + gw) * 4 + part];
            sm[pixl * 5 + part] = v;
        }
    }
    __syncthreads();

    v4i acc[4];
#pragma unroll
    for (int i = 0; i < 4; ++i) acc[i] = (v4i){0, 0, 0, 0};

#pragma unroll
    for (int kh = 0; kh < 3; ++kh) {
#pragma unroll
        for (int kw = 0; kw < 3; ++kw) {
            v4i af = a[kh * 3 + kw];
#pragma unroll
            for (int nt = 0; nt < 4; ++nt) {
                int sw = nt * 16 + col + kw - 1;
                bool valid = (unsigned)sw < 56u;
                v4i bf = sm[(kh * W56 + (valid ? sw : 0)) * 5 + koff];
                if (!valid) { bf[0] = 0; bf[1] = 0; bf[2] = 0; bf[3] = 0; }
                acc[nt] = __builtin_amdgcn_mfma_i32_16x16x64_i8(af, bf, acc[nt], 0, 0, 0);
            }
        }
    }

    // prefetch residual xq dwords for ALL 4 phase-B steps (16 VGPRs);
    // latency hides under the phase-A epilogue + barrier.
    int pxc[4];
#pragma unroll
    for (int nt = 0; nt < 4; ++nt) {
        int px = nt * 16 + col;
        pxc[nt] = px < 56 ? px : 55;
    }
    const unsigned char* xqb = xq + ((size_t)b * HW + r0 * W56) * 256 + wv * 64 + rowb;
    int xqv[4][4];                                // [t][nt]
#pragma unroll
    for (int t = 0; t < 4; ++t)
#pragma unroll
        for (int nt = 0; nt < 4; ++nt)
            xqv[t][nt] = *(const int*)(xqb + (size_t)pxc[nt] * 256 + t * 16);

    {   // phase A epilogue: requant + bn2, perm-pack -> t2s (B-frag layout)
        const int cm0 = conv_m0[1], csh = conv_shift[1], czo = conv_zout[1];
        const int bm0 = bn_m0[1], bsh = bn_shift[1], bzo = bn_zout[1];
        const int zin3 = conv_zin[2];
        const long long cbv = 1LL << (30 + csh);
        const long long ccp = cbv + (1LL << 30), ccn = cbv + 1 - (1LL << 30);
        const int cshm1 = csh - 1;
        const long long bbv = 1LL << (30 + bsh);
        const long long bcp = bbv + (1LL << 30), bcn = bbv + 1 - (1LL << 30);
        const int bshm1 = bsh - 1;
        int bw[4], bbx[4];
#pragma unroll
        for (int r = 0; r < 4; ++r) {
            bw[r] = (int)bn2_w[co0 + rowb + r];
            bbx[r] = (int)bn2_b[co0 + rowb + r] - czo * bw[r];
        }
#pragma unroll
        for (int nt = 0; nt < 4; ++nt) {
            int pix = nt * 16 + col;
            int e[4];
#pragma unroll
            for (int r = 0; r < 4; ++r) {
                int qv = rq_apply(acc[nt][r], cm0, ccp, ccn, cshm1, czo);
                int a2 = qv * bw[r] + bbx[r];
                int q2 = rq_apply(a2, bm0, bcp, bcn, bshm1, bzo);
                e[r] = q2 - zin3;
            }
            *(unsigned*)((char*)t2s + (size_t)(pix * 5 + wv) * 16 + koff * 4) =
                pk4x(e[0], e[1], e[2], e[3]);
        }
    }
    __syncthreads();                              // t2s ready

    // ---- phase B: 1x1 64->256 + bn3 + residual add (register-only loop) ----
    const int cm0 = conv_m0[2], csh = conv_shift[2], czo = conv_zout[2];
    const int bm0 = bn_m0[2], bsh = bn_shift[2], bzo = bn_zout[2];
    const long long cb3 = 1LL << (30 + csh);
    const long long ccp = cb3 + (1LL << 30), ccn = cb3 + 1 - (1LL << 30);
    const int cshm1 = csh - 1;
    const long long bb3 = 1LL << (30 + bsh);
    const long long bcp = bb3 + (1LL << 30), bcn = bb3 + 1 - (1LL << 30);
    const int bshm1 = bsh - 1;
    const int az0 = add_z[0], az1 = add_z[1];
    const int corr = 128 - az0;                   // xq holds x-128
    const int am0 = add_m0[0], am1 = add_m0[1];
    const int ash0 = add_shift[0], ash1 = add_shift[1];
    const long long a0b = 1LL << (30 + ash0);
    const long long acp0 = a0b + (1LL << 30), acn0 = a0b + 1 - (1LL << 30);
    const int ashm0 = ash0 - 1;
    const long long a1b = 1LL << (30 + ash1);
    const long long acp1 = a1b + (1LL << 30), acn1 = a1b + 1 - (1LL << 30);
    const int ashm1 = ash1 - 1;
    const int azout = add_zout[0];

    // bn3 params for all 4 steps (loads scheduled early in phase B)
    int bw3[4][4], bbx3[4][4];
#pragma unroll
    for (int s = 0; s < 4; ++s)
#pragma unroll
        for (int r = 0; r < 4; ++r) {
            bw3[s][r] = (int)bn3_w[wv * 64 + s * 16 + rowb + r];
            bbx3[s][r] = (int)bn3_b[wv * 64 + s * 16 + rowb + r] - czo * bw3[s][r];
        }

    v4i bf[4];                                    // t2s read ONCE
#pragma unroll
    for (int nt = 0; nt < 4; ++nt) bf[nt] = t2s[(nt * 16 + col) * 5 + koff];

    int* ob = out + (size_t)b * CIN * HW + (size_t)r0 * W56;

#pragma unroll
    for (int t = 0; t < 4; ++t) {
        const int c0 = wv * 64 + t * 16;
        v4i acc3[4];
#pragma unroll
        for (int i = 0; i < 4; ++i) acc3[i] = (v4i){0, 0, 0, 0};
#pragma unroll
        for (int nt = 0; nt < 4; ++nt)
            acc3[nt] = __builtin_amdgcn_mfma_i32_16x16x64_i8(a3x[t], bf[nt], acc3[nt], 0, 0, 0);
#pragma unroll
        for (int nt = 0; nt < 4; ++nt) {
            int px = nt * 16 + col;
            bool st = px < 56;
#pragma unroll
            for (int r = 0; r < 4; ++r) {
                int sx = (int)(signed char)(((unsigned)xqv[t][nt]) >> (8 * r));
                int qv = rq_apply(acc3[nt][r], cm0, ccp, ccn, cshm1, czo);
                int a2 = qv * bw3[t][r] + bbx3[t][r];
                int q2 = rq_apply(a2, bm0, bcp, bcn, bshm1, bzo);
                int ra = ms_apply(sx + corr, am0, acp0, acn0, ashm0);
                int rb = ms_apply(q2 - az1, am1, acp1, acn1, ashm1);
                int res = ra + rb + azout;
                res = res < 0 ? 0 : (res > 255 ? 255 : res);
                if (st) ob[(size_t)(c0 + rowb + r) * HW + px] = res;
            }
        }
    }
}

extern "C" void kernel_launch(void* const* d_in, const int* in_sizes, int n_in,
                              void* d_out, int out_size, void* d_ws, size_t ws_size,
                              hipStream_t stream) {
    const int* x = (const int*)d_in[0];
    const float* w1 = (const float*)d_in[1];
    const float* w2 = (const float*)d_in[2];
    const float* w3 = (const float*)d_in[3];
    const float* bn1_w = (const float*)d_in[4];
    const float* bn1_b = (const float*)d_in[5];
    const float* bn2_w = (const float*)d_in[6];
    const float* bn2_b = (const float*)d_in[7];
    const float* bn3_w = (const float*)d_in[8];
    const float* bn3_b = (const float*)d_in[9];
    const int* conv_zin = (const int*)d_in[10];
    const int* conv_m0 = (const int*)d_in[11];
    const int* conv_shift = (const int*)d_in[12];
    const int* conv_zout = (const int*)d_in[13];
    const int* bn_m0 = (const int*)d_in[14];
    const int* bn_shift = (const int*)d_in[15];
    const int* bn_zout = (const int*)d_in[16];
    const int* add_z = (const int*)d_in[17];
    const int* add_m0 = (const int*)d_in[18];
    const int* add_shift = (const int*)d_in[19];
    const int* add_zout = (const int*)d_in[20];

    v4i* wp = (v4i*)d_ws;
    int* wsum1 = (int*)((char*)d_ws + WP_BYTES);
    signed char* t1 = (signed char*)d_ws + WP_BYTES + WSUM_BYTES;
    unsigned char* xq = (unsigned char*)t1 + T1_BYTES;

    const v4i* wp1 = wp;
    const v4i* wp2 = wp + 16 * 64;
    const v4i* wp3 = wp + 52 * 64;

    k_prep<<<dim3(18), dim3(256), 0, stream>>>(w1, w2, w3, wp, wsum1);
    k_pack<<<dim3(49, 32), dim3(256), 0, stream>>>(x, xq);
    k_conv1<<<dim3(28, 32), dim3(256), 0, stream>>>(xq, wp1, wsum1, bn1_w, bn1_b,
        conv_zin, conv_m0, conv_shift, conv_zout, bn_m0, bn_shift, bn_zout, t1);
    k_conv23<<<dim3(56, 32), dim3(256), 0, stream>>>(t1, wp2, wp3,
        bn2_w, bn2_b, bn3_w, bn3_b, xq,
        conv_zin, conv_m0, conv_shift, conv_zout, bn_m0, bn_shift, bn_zout,
        add_z, add_m0, add_shift, add_zout, (int*)d_out);
}

// Round 6
// 284.687 us; speedup vs baseline: 1.0504x; 1.0504x over previous
//
#include <hip/hip_runtime.h>

// QuantizedBottleneck via i8 MFMA implicit GEMM. Exact integer math.
//   prep  : pack MFMA A-fragments (w1/w2/w3 -> i8) + wsum1 into d_ws
//   pack1 : FUSED x->xq transpose-pack + conv1 (1x1 256->64 + bn1 -> t1).
//           One block = 64 px x 256 ch tile staged in LDS once; emits
//           xq [b][px][256] i8 (=x-128), and runs conv1 MFMA off the same
//           LDS tile (B-frag = 2x ds_read_b64 from 66-dword padded rows).
//   conv23: fused 3x3 64->64 pad1 + bn2 -> LDS, then 1x1 64->256 + bn3 +
//           residual add -> out int32. Residual from xq (16 dwords/thread).
// Requant uses the exact single-shift identity:
//   ((p+nudge)>>31 + 2^(sh-1))>>sh == (p + nudge + 2^(30+sh)) >> (31+sh)
// xq holds x-128; conv1 corrects acc by (128-zin)*wsum; residual uses
// sx + (128 - az0) == x - az0.
// MFMA 16x16x64_i8: A[m=lane&15][k=(lane>>4)*16+j], B[k][n=lane&15],
// C/D: col=lane&15, row=(lane>>4)*4+reg.

typedef int v4i __attribute__((ext_vector_type(4)));

#define BATCH 32
#define CIN 256
#define CMID 64
#define HW 3136
#define W56 56

#define WP_BYTES ((size_t)68 * 64 * 16)
#define WSUM_BYTES ((size_t)64 * 4)
#define T1_BYTES ((size_t)BATCH * HW * CMID)

__device__ __forceinline__ int rq_apply(int acc, int m0, long long cp, long long cn,
                                        int shm1, int zo) {
    long long prod = (long long)acc * m0;
    prod += (prod >= 0) ? cp : cn;
    int hi = (int)((unsigned long long)prod >> 32);
    int v = (hi >> shm1) + zo;
    return v < 0 ? 0 : (v > 255 ? 255 : v);
}

__device__ __forceinline__ int ms_apply(int xin, int m0, long long cp, long long cn,
                                        int shm1) {
    long long prod = (long long)xin * m0;
    prod += (prod >= 0) ? cp : cn;
    return ((int)((unsigned long long)prod >> 32)) >> shm1;
}

// gather byte0 of four ints -> one dword (3 x v_perm_b32)
__device__ __forceinline__ unsigned int pk4x(int a0, int a1, int a2, int a3) {
    unsigned p01 = __builtin_amdgcn_perm((unsigned)a1, (unsigned)a0, 0x00000400u);
    unsigned p23 = __builtin_amdgcn_perm((unsigned)a3, (unsigned)a2, 0x04000000u);
    return __builtin_amdgcn_perm(p23, p01, 0x07060100u);
}

__device__ __forceinline__ v4i pack16f(const float* src, int stride) {
    v4i r;
#pragma unroll
    for (int d = 0; d < 4; ++d) {
        unsigned int u = 0;
#pragma unroll
        for (int by = 0; by < 4; ++by) {
            int v = (int)src[(d * 4 + by) * stride];
            u |= ((unsigned int)(v & 255)) << (8 * by);
        }
        r[d] = (int)u;
    }
    return r;
}

// -------- prep: fragsets w1 [0,16), w2 [16,52), w3 [52,68); block 17: wsum1 --
__global__ __launch_bounds__(256) void k_prep(
    const float* __restrict__ w1, const float* __restrict__ w2,
    const float* __restrict__ w3, v4i* __restrict__ wp, int* __restrict__ wsum)
{
    if (blockIdx.x < 17) {
        int id = blockIdx.x * 256 + threadIdx.x;
        int fid = id >> 6, lane = id & 63;
        int col = lane & 15, ci0 = (lane >> 4) * 16;
        const float* src;
        int stride;
        if (fid < 16) {
            int wv = fid >> 2, ks = fid & 3;
            src = w1 + (size_t)(wv * 16 + col) * 256 + ks * 64 + ci0;
            stride = 1;
        } else if (fid < 52) {
            int i = fid - 16, wv = i / 9, t = i - wv * 9;
            src = w2 + ((size_t)(wv * 16 + col) * 64 + ci0) * 9 + t;
            stride = 9;
        } else {
            int s = fid - 52;
            src = w3 + (size_t)(s * 16 + col) * 64 + ci0;
            stride = 1;
        }
        wp[fid * 64 + lane] = pack16f(src, stride);
    } else {
        // wsum1[co] = sum_ci w1[co][ci]  (4 threads per channel)
        int ch = threadIdx.x >> 2, t4 = threadIdx.x & 3;
        int s = 0;
        for (int i = 0; i < 64; ++i) s += (int)w1[(size_t)ch * 256 + t4 * 64 + i];
        s += __shfl_xor(s, 1);
        s += __shfl_xor(s, 2);
        if (t4 == 0) wsum[ch] = s;
    }
}

// -------- pack1: x -> xq  AND  conv1 (1x1 256->64 + bn1) -> t1 --------------
// grid (49, 32): 64-px x 256-ch tile. Stage int32 x as packed (x-128) i8 into
// LDS [64 px][66 dwords] (264B rows, pad breaks pow2 banks). Then:
//  (a) write xq rows (v4i stores, coalesced)
//  (b) each wave wv computes out-ch [wv*16,+16): 4 ks x 4 nt MFMAs with
//      B-frags read from LDS as 2x qword (8B-aligned, ~4-way conflicts).
__global__ __launch_bounds__(256, 4) void k_pack1(
    const int* __restrict__ x, const v4i* __restrict__ wp1,
    const int* __restrict__ wsum1,
    const float* __restrict__ bn_w, const float* __restrict__ bn_b,
    const int* __restrict__ conv_zin, const int* __restrict__ conv_m0,
    const int* __restrict__ conv_shift, const int* __restrict__ conv_zout,
    const int* __restrict__ bn_m0, const int* __restrict__ bn_shift,
    const int* __restrict__ bn_zout, signed char* __restrict__ t1,
    unsigned char* __restrict__ xq)
{
    __shared__ unsigned int lds[64 * 66];          // 16.9 KB
    const int tid = threadIdx.x, lane = tid & 63, wv = tid >> 6;
    const int b = blockIdx.y;
    const int px0 = blockIdx.x * 64;

    // A-frags first (independent loads, hide under staging)
    v4i a[4];
#pragma unroll
    for (int ks = 0; ks < 4; ++ks) a[ks] = wp1[(wv * 4 + ks) * 64 + lane];

    // ---- stage: thread (px=tid&63, cb=(tid>>6)*64) packs 64 ch of one px --
    const int spx = tid & 63, cb = (tid >> 6) * 64;
    const int* xb = x + (size_t)b * CIN * HW + px0 + spx;
#pragma unroll
    for (int i = 0; i < 16; ++i) {
        int ch = cb + i * 4;
        int v0 = xb[(size_t)(ch + 0) * HW];
        int v1 = xb[(size_t)(ch + 1) * HW];
        int v2 = xb[(size_t)(ch + 2) * HW];
        int v3 = xb[(size_t)(ch + 3) * HW];
        lds[spx * 66 + (ch >> 2)] = pk4x(v0, v1, v2, v3) ^ 0x80808080u;
    }
    __syncthreads();

    // ---- (a) xq store: 4 x v4i per thread, row-major coalesced ------------
    unsigned char* xqb = xq + ((size_t)b * HW + px0) * 256;
#pragma unroll
    for (int i = 0; i < 4; ++i) {
        int flat = tid + i * 256;
        int row = flat >> 4, off = (flat & 15) * 4;   // dword offset in row
        v4i o;
        o[0] = (int)lds[row * 66 + off + 0];
        o[1] = (int)lds[row * 66 + off + 1];
        o[2] = (int)lds[row * 66 + off + 2];
        o[3] = (int)lds[row * 66 + off + 3];
        *(v4i*)(xqb + (size_t)row * 256 + off * 4) = o;
    }

    // ---- (b) conv1 MFMA off the same LDS tile -----------------------------
    const int col = lane & 15, koff = lane >> 4;
    const int co0 = wv * 16;
    v4i acc[4];
#pragma unroll
    for (int i = 0; i < 4; ++i) acc[i] = (v4i){0, 0, 0, 0};

    const unsigned long long* ldsq = (const unsigned long long*)lds;
#pragma unroll
    for (int ks = 0; ks < 4; ++ks) {
#pragma unroll
        for (int nt = 0; nt < 4; ++nt) {
            int p = nt * 16 + col;
            int qi = p * 33 + ks * 8 + koff * 2;   // qword index (row = 33 qw)
            unsigned long long q0 = ldsq[qi];
            unsigned long long q1 = ldsq[qi + 1];
            v4i bf;
            bf[0] = (int)(unsigned)q0; bf[1] = (int)(q0 >> 32);
            bf[2] = (int)(unsigned)q1; bf[3] = (int)(q1 >> 32);
            acc[nt] = __builtin_amdgcn_mfma_i32_16x16x64_i8(a[ks], bf, acc[nt], 0, 0, 0);
        }
    }

    // ---- conv1+bn1 epilogue -> t1 -----------------------------------------
    const int zin = conv_zin[0];
    const int corr0 = 128 - zin;                   // acc was computed vs x-128
    const int cm0 = conv_m0[0], csh = conv_shift[0], czo = conv_zout[0];
    const int bm0 = bn_m0[0], bsh = bn_shift[0], bzo = bn_zout[0];
    const int zin2 = conv_zin[1];
    const long long cbv = 1LL << (30 + csh);
    const long long ccp = cbv + (1LL << 30), ccn = cbv + 1 - (1LL << 30);
    const int cshm1 = csh - 1;
    const long long bbv = 1LL << (30 + bsh);
    const long long bcp = bbv + (1LL << 30), bcn = bbv + 1 - (1LL << 30);
    const int bshm1 = bsh - 1;
    const int rowb = koff * 4;
    int bw[4], bbx[4], ws[4];
#pragma unroll
    for (int r = 0; r < 4; ++r) {
        bw[r] = (int)bn_w[co0 + rowb + r];
        bbx[r] = (int)bn_b[co0 + rowb + r] - czo * bw[r];
        ws[r] = wsum1[co0 + rowb + r];
    }
#pragma unroll
    for (int nt = 0; nt < 4; ++nt) {
        int n = b * HW + px0 + nt * 16 + col;
        int e[4];
#pragma unroll
        for (int r = 0; r < 4; ++r) {
            int av = acc[nt][r] + corr0 * ws[r];
            int qv = rq_apply(av, cm0, ccp, ccn, cshm1, czo);
            int a2 = qv * bw[r] + bbx[r];
            int q2 = rq_apply(a2, bm0, bcp, bcn, bshm1, bzo);
            e[r] = q2 - zin2;
        }
        *(unsigned*)(t1 + (size_t)n * 64 + co0 + rowb) = pk4x(e[0], e[1], e[2], e[3]);
    }
}

// -------- conv23: fused 3x3+bn2 (-> LDS) then 1x1 64->256 + bn3 + residual --
// grid (56, 32): 1 output row (64 px padded, 56 valid) x batch.
// Phase A: conv2 over 3 halo rows in sm -> t2s LDS (B-frag layout).
//          Residual xq dwords (all 4 steps) prefetched under phase-A epilogue.
// Phase B: bf[4] read once from t2s; 4 register-only MFMA+epilogue steps.
__global__ __launch_bounds__(256, 4) void k_conv23(
    const signed char* __restrict__ t1, const v4i* __restrict__ wp2,
    const v4i* __restrict__ wp3,
    const float* __restrict__ bn2_w, const float* __restrict__ bn2_b,
    const float* __restrict__ bn3_w, const float* __restrict__ bn3_b,
    const unsigned char* __restrict__ xq,
    const int* __restrict__ conv_zin, const int* __restrict__ conv_m0,
    const int* __restrict__ conv_shift, const int* __restrict__ conv_zout,
    const int* __restrict__ bn_m0, const int* __restrict__ bn_shift,
    const int* __restrict__ bn_zout,
    const int* __restrict__ add_z, const int* __restrict__ add_m0,
    const int* __restrict__ add_shift, const int* __restrict__ add_zout,
    int* __restrict__ out)
{
    __shared__ v4i sm[840];                       // 3 rows x 56 px x 80 B
    __shared__ v4i t2s[320];                      // 64 px x 80 B
    const int tid = threadIdx.x, lane = tid & 63, wv = tid >> 6;
    const int col = lane & 15, koff = lane >> 4;
    const int b = blockIdx.y;
    const int r0 = blockIdx.x;
    const int co0 = wv * 16, rowb = koff * 4;

    v4i a[9];
#pragma unroll
    for (int t = 0; t < 9; ++t) a[t] = wp2[(wv * 9 + t) * 64 + lane];
    v4i a3x[4];
#pragma unroll
    for (int s = 0; s < 4; ++s) a3x[s] = wp3[(wv * 4 + s) * 64 + lane];

    const v4i* t1v = (const v4i*)t1;
#pragma unroll
    for (int k = 0; k < 3; ++k) {
        int idx = tid + k * 256;
        if (idx < 672) {                          // 168 px x 4 parts
            int pixl = idx >> 2, part = idx & 3;
            int lrow = pixl / W56, gw = pixl - lrow * W56;
            int grow = r0 - 1 + lrow;
            v4i v = (v4i){0, 0, 0, 0};
            if ((unsigned)grow < 56u)
                v = t1v[((size_t)b * HW + grow * W56 + gw) * 4 + part];
            sm[pixl * 5 + part] = v;
        }
    }
    __syncthreads();

    v4i acc[4];
#pragma unroll
    for (int i = 0; i < 4; ++i) acc[i] = (v4i){0, 0, 0, 0};

#pragma unroll
    for (int kh = 0; kh < 3; ++kh) {
#pragma unroll
        for (int kw = 0; kw < 3; ++kw) {
            v4i af = a[kh * 3 + kw];
#pragma unroll
            for (int nt = 0; nt < 4; ++nt) {
                int sw = nt * 16 + col + kw - 1;
                bool valid = (unsigned)sw < 56u;
                v4i bf = sm[(kh * W56 + (valid ? sw : 0)) * 5 + koff];
                if (!valid) { bf[0] = 0; bf[1] = 0; bf[2] = 0; bf[3] = 0; }
                acc[nt] = __builtin_amdgcn_mfma_i32_16x16x64_i8(af, bf, acc[nt], 0, 0, 0);
            }
        }
    }

    // prefetch residual xq dwords for ALL 4 phase-B steps (16 VGPRs);
    // latency hides under the phase-A epilogue + barrier.
    int pxc[4];
#pragma unroll
    for (int nt = 0; nt < 4; ++nt) {
        int px = nt * 16 + col;
        pxc[nt] = px < 56 ? px : 55;
    }
    const unsigned char* xqb = xq + ((size_t)b * HW + r0 * W56) * 256 + wv * 64 + rowb;
    int xqv[4][4];                                // [t][nt]
#pragma unroll
    for (int t = 0; t < 4; ++t)
#pragma unroll
        for (int nt = 0; nt < 4; ++nt)
            xqv[t][nt] = *(const int*)(xqb + (size_t)pxc[nt] * 256 + t * 16);

    {   // phase A epilogue: requant + bn2, perm-pack -> t2s (B-frag layout)
        const int cm0 = conv_m0[1], csh = conv_shift[1], czo = conv_zout[1];
        const int bm0 = bn_m0[1], bsh = bn_shift[1], bzo = bn_zout[1];
        const int zin3 = conv_zin[2];
        const long long cbv = 1LL << (30 + csh);
        const long long ccp = cbv + (1LL << 30), ccn = cbv + 1 - (1LL << 30);
        const int cshm1 = csh - 1;
        const long long bbv = 1LL << (30 + bsh);
        const long long bcp = bbv + (1LL << 30), bcn = bbv + 1 - (1LL << 30);
        const int bshm1 = bsh - 1;
        int bw[4], bbx[4];
#pragma unroll
        for (int r = 0; r < 4; ++r) {
            bw[r] = (int)bn2_w[co0 + rowb + r];
            bbx[r] = (int)bn2_b[co0 + rowb + r] - czo * bw[r];
        }
#pragma unroll
        for (int nt = 0; nt < 4; ++nt) {
            int pix = nt * 16 + col;
            int e[4];
#pragma unroll
            for (int r = 0; r < 4; ++r) {
                int qv = rq_apply(acc[nt][r], cm0, ccp, ccn, cshm1, czo);
                int a2 = qv * bw[r] + bbx[r];
                int q2 = rq_apply(a2, bm0, bcp, bcn, bshm1, bzo);
                e[r] = q2 - zin3;
            }
            *(unsigned*)((char*)t2s + (size_t)(pix * 5 + wv) * 16 + koff * 4) =
                pk4x(e[0], e[1], e[2], e[3]);
        }
    }
    __syncthreads();                              // t2s ready

    // ---- phase B: 1x1 64->256 + bn3 + residual add (register-only loop) ----
    const int cm0 = conv_m0[2], csh = conv_shift[2], czo = conv_zout[2];
    const int bm0 = bn_m0[2], bsh = bn_shift[2], bzo = bn_zout[2];
    const long long cb3 = 1LL << (30 + csh);
    const long long ccp = cb3 + (1LL << 30), ccn = cb3 + 1 - (1LL << 30);
    const int cshm1 = csh - 1;
    const long long bb3 = 1LL << (30 + bsh);
    const long long bcp = bb3 + (1LL << 30), bcn = bb3 + 1 - (1LL << 30);
    const int bshm1 = bsh - 1;
    const int az0 = add_z[0], az1 = add_z[1];
    const int corr = 128 - az0;                   // xq holds x-128
    const int am0 = add_m0[0], am1 = add_m0[1];
    const int ash0 = add_shift[0], ash1 = add_shift[1];
    const long long a0b = 1LL << (30 + ash0);
    const long long acp0 = a0b + (1LL << 30), acn0 = a0b + 1 - (1LL << 30);
    const int ashm0 = ash0 - 1;
    const long long a1b = 1LL << (30 + ash1);
    const long long acp1 = a1b + (1LL << 30), acn1 = a1b + 1 - (1LL << 30);
    const int ashm1 = ash1 - 1;
    const int azout = add_zout[0];

    // bn3 params for all 4 steps (loads scheduled early in phase B)
    int bw3[4][4], bbx3[4][4];
#pragma unroll
    for (int s = 0; s < 4; ++s)
#pragma unroll
        for (int r = 0; r < 4; ++r) {
            bw3[s][r] = (int)bn3_w[wv * 64 + s * 16 + rowb + r];
            bbx3[s][r] = (int)bn3_b[wv * 64 + s * 16 + rowb + r] - czo * bw3[s][r];
        }

    v4i bf[4];                                    // t2s read ONCE
#pragma unroll
    for (int nt = 0; nt < 4; ++nt) bf[nt] = t2s[(nt * 16 + col) * 5 + koff];

    int* ob = out + (size_t)b * CIN * HW + (size_t)r0 * W56;

#pragma unroll
    for (int t = 0; t < 4; ++t) {
        const int c0 = wv * 64 + t * 16;
        v4i acc3[4];
#pragma unroll
        for (int i = 0; i < 4; ++i) acc3[i] = (v4i){0, 0, 0, 0};
#pragma unroll
        for (int nt = 0; nt < 4; ++nt)
            acc3[nt] = __builtin_amdgcn_mfma_i32_16x16x64_i8(a3x[t], bf[nt], acc3[nt], 0, 0, 0);
#pragma unroll
        for (int nt = 0; nt < 4; ++nt) {
            int px = nt * 16 + col;
            bool st = px < 56;
#pragma unroll
            for (int r = 0; r < 4; ++r) {
                int sx = (int)(signed char)(((unsigned)xqv[t][nt]) >> (8 * r));
                int qv = rq_apply(acc3[nt][r], cm0, ccp, ccn, cshm1, czo);
                int a2 = qv * bw3[t][r] + bbx3[t][r];
                int q2 = rq_apply(a2, bm0, bcp, bcn, bshm1, bzo);
                int ra = ms_apply(sx + corr, am0, acp0, acn0, ashm0);
                int rb = ms_apply(q2 - az1, am1, acp1, acn1, ashm1);
                int res = ra + rb + azout;
                res = res < 0 ? 0 : (res > 255 ? 255 : res);
                if (st) ob[(size_t)(c0 + rowb + r) * HW + px] = res;
            }
        }
    }
}

extern "C" void kernel_launch(void* const* d_in, const int* in_sizes, int n_in,
                              void* d_out, int out_size, void* d_ws, size_t ws_size,
                              hipStream_t stream) {
    const int* x = (const int*)d_in[0];
    const float* w1 = (const float*)d_in[1];
    const float* w2 = (const float*)d_in[2];
    const float* w3 = (const float*)d_in[3];
    const float* bn1_w = (const float*)d_in[4];
    const float* bn1_b = (const float*)d_in[5];
    const float* bn2_w = (const float*)d_in[6];
    const float* bn2_b = (const float*)d_in[7];
    const float* bn3_w = (const float*)d_in[8];
    const float* bn3_b = (const float*)d_in[9];
    const int* conv_zin = (const int*)d_in[10];
    const int* conv_m0 = (const int*)d_in[11];
    const int* conv_shift = (const int*)d_in[12];
    const int* conv_zout = (const int*)d_in[13];
    const int* bn_m0 = (const int*)d_in[14];
    const int* bn_shift = (const int*)d_in[15];
    const int* bn_zout = (const int*)d_in[16];
    const int* add_z = (const int*)d_in[17];
    const int* add_m0 = (const int*)d_in[18];
    const int* add_shift = (const int*)d_in[19];
    const int* add_zout = (const int*)d_in[20];

    v4i* wp = (v4i*)d_ws;
    int* wsum1 = (int*)((char*)d_ws + WP_BYTES);
    signed char* t1 = (signed char*)d_ws + WP_BYTES + WSUM_BYTES;
    unsigned char* xq = (unsigned char*)t1 + T1_BYTES;

    const v4i* wp1 = wp;
    const v4i* wp2 = wp + 16 * 64;
    const v4i* wp3 = wp + 52 * 64;

    k_prep<<<dim3(18), dim3(256), 0, stream>>>(w1, w2, w3, wp, wsum1);
    k_pack1<<<dim3(49, 32), dim3(256), 0, stream>>>(x, wp1, wsum1, bn1_w, bn1_b,
        conv_zin, conv_m0, conv_shift, conv_zout, bn_m0, bn_shift, bn_zout, t1, xq);
    k_conv23<<<dim3(56, 32), dim3(256), 0, stream>>>(t1, wp2, wp3,
        bn2_w, bn2_b, bn3_w, bn3_b, xq,
        conv_zin, conv_m0, conv_shift, conv_zout, bn_m0, bn_shift, bn_zout,
        add_z, add_m0, add_shift, add_zout, (int*)d_out);
}

// Round 7
// 282.460 us; speedup vs baseline: 1.0587x; 1.0079x over previous
//
#include <hip/hip_runtime.h>

// QuantizedBottleneck via i8 MFMA implicit GEMM. Exact integer math.
//   prep  : pack MFMA A-fragments (w1/w2/w3 -> i8) + wsum1 into d_ws
//   pack1 : FUSED x->xq transpose-pack + conv1 (1x1 256->64 + bn1 -> t1).
//           One block = 64 px x 256 ch tile staged in LDS once (vectorized
//           v4i x loads: 16 instrs/thread, not 64); emits xq [b][px][256] i8
//           (=x-128), and runs conv1 MFMA off the same LDS tile.
//   conv23: fused 3x3 64->64 pad1 + bn2 -> LDS, then 1x1 64->256 + bn3 +
//           residual add -> out int32. Residual from xq (16 dwords/thread).
// Requant uses the exact single-shift identity:
//   ((p+nudge)>>31 + 2^(sh-1))>>sh == (p + nudge + 2^(30+sh)) >> (31+sh)
// xq holds x-128; conv1 corrects acc by (128-zin)*wsum; residual uses
// sx + (128 - az0) == x - az0.
// MFMA 16x16x64_i8: A[m=lane&15][k=(lane>>4)*16+j], B[k][n=lane&15],
// C/D: col=lane&15, row=(lane>>4)*4+reg.

typedef int v4i __attribute__((ext_vector_type(4)));

#define BATCH 32
#define CIN 256
#define CMID 64
#define HW 3136
#define W56 56

#define WP_BYTES ((size_t)68 * 64 * 16)
#define WSUM_BYTES ((size_t)64 * 4)
#define T1_BYTES ((size_t)BATCH * HW * CMID)

__device__ __forceinline__ int rq_apply(int acc, int m0, long long cp, long long cn,
                                        int shm1, int zo) {
    long long prod = (long long)acc * m0;
    prod += (prod >= 0) ? cp : cn;
    int hi = (int)((unsigned long long)prod >> 32);
    int v = (hi >> shm1) + zo;
    return v < 0 ? 0 : (v > 255 ? 255 : v);
}

__device__ __forceinline__ int ms_apply(int xin, int m0, long long cp, long long cn,
                                        int shm1) {
    long long prod = (long long)xin * m0;
    prod += (prod >= 0) ? cp : cn;
    return ((int)((unsigned long long)prod >> 32)) >> shm1;
}

// gather byte0 of four ints -> one dword (3 x v_perm_b32)
__device__ __forceinline__ unsigned int pk4x(int a0, int a1, int a2, int a3) {
    unsigned p01 = __builtin_amdgcn_perm((unsigned)a1, (unsigned)a0, 0x00000400u);
    unsigned p23 = __builtin_amdgcn_perm((unsigned)a3, (unsigned)a2, 0x04000000u);
    return __builtin_amdgcn_perm(p23, p01, 0x07060100u);
}

__device__ __forceinline__ v4i pack16f(const float* src, int stride) {
    v4i r;
#pragma unroll
    for (int d = 0; d < 4; ++d) {
        unsigned int u = 0;
#pragma unroll
        for (int by = 0; by < 4; ++by) {
            int v = (int)src[(d * 4 + by) * stride];
            u |= ((unsigned int)(v & 255)) << (8 * by);
        }
        r[d] = (int)u;
    }
    return r;
}

// -------- prep: fragsets w1 [0,16), w2 [16,52), w3 [52,68); block 17: wsum1 --
__global__ __launch_bounds__(256) void k_prep(
    const float* __restrict__ w1, const float* __restrict__ w2,
    const float* __restrict__ w3, v4i* __restrict__ wp, int* __restrict__ wsum)
{
    if (blockIdx.x < 17) {
        int id = blockIdx.x * 256 + threadIdx.x;
        int fid = id >> 6, lane = id & 63;
        int col = lane & 15, ci0 = (lane >> 4) * 16;
        const float* src;
        int stride;
        if (fid < 16) {
            int wv = fid >> 2, ks = fid & 3;
            src = w1 + (size_t)(wv * 16 + col) * 256 + ks * 64 + ci0;
            stride = 1;
        } else if (fid < 52) {
            int i = fid - 16, wv = i / 9, t = i - wv * 9;
            src = w2 + ((size_t)(wv * 16 + col) * 64 + ci0) * 9 + t;
            stride = 9;
        } else {
            int s = fid - 52;
            src = w3 + (size_t)(s * 16 + col) * 64 + ci0;
            stride = 1;
        }
        wp[fid * 64 + lane] = pack16f(src, stride);
    } else {
        // wsum1[co] = sum_ci w1[co][ci]  (4 threads per channel)
        int ch = threadIdx.x >> 2, t4 = threadIdx.x & 3;
        int s = 0;
        for (int i = 0; i < 64; ++i) s += (int)w1[(size_t)ch * 256 + t4 * 64 + i];
        s += __shfl_xor(s, 1);
        s += __shfl_xor(s, 2);
        if (t4 == 0) wsum[ch] = s;
    }
}

// -------- pack1: x -> xq  AND  conv1 (1x1 256->64 + bn1) -> t1 --------------
// grid (49, 32): 64-px x 256-ch tile. Stage int32 x as packed (x-128) i8 into
// LDS [64 px][66 dwords] (264B rows, pad breaks pow2 banks). Then:
//  (a) write xq rows (v4i stores, coalesced)
//  (b) each wave wv computes out-ch [wv*16,+16): 4 ks x 4 nt MFMAs with
//      B-frags read from LDS as 2x qword (8B-aligned).
__global__ __launch_bounds__(256, 4) void k_pack1(
    const int* __restrict__ x, const v4i* __restrict__ wp1,
    const int* __restrict__ wsum1,
    const float* __restrict__ bn_w, const float* __restrict__ bn_b,
    const int* __restrict__ conv_zin, const int* __restrict__ conv_m0,
    const int* __restrict__ conv_shift, const int* __restrict__ conv_zout,
    const int* __restrict__ bn_m0, const int* __restrict__ bn_shift,
    const int* __restrict__ bn_zout, signed char* __restrict__ t1,
    unsigned char* __restrict__ xq)
{
    __shared__ unsigned int lds[64 * 66];          // 16.9 KB
    const int tid = threadIdx.x, lane = tid & 63, wv = tid >> 6;
    const int b = blockIdx.y;
    const int px0 = blockIdx.x * 64;

    // A-frags first (independent loads, hide under staging)
    v4i a[4];
#pragma unroll
    for (int ks = 0; ks < 4; ++ks) a[ks] = wp1[(wv * 4 + ks) * 64 + lane];

    // ---- stage (vectorized): thread (pxg=(tid&15)*4, chg=tid>>4) loads
    //      v4i (4 px) for each of its 16 channels, in two 8-ch chunks.
    const int pxg = (tid & 15) * 4, chg = tid >> 4;
    const int* xb2 = x + (size_t)b * CIN * HW + px0 + pxg;
#pragma unroll
    for (int h = 0; h < 2; ++h) {
        v4i v[8];
#pragma unroll
        for (int k = 0; k < 8; ++k)
            v[k] = *(const v4i*)(xb2 + (size_t)(chg * 16 + h * 8 + k) * HW);
#pragma unroll
        for (int j = 0; j < 4; ++j)
#pragma unroll
            for (int q = 0; q < 2; ++q) {
                unsigned dw = pk4x(v[q * 4 + 0][j], v[q * 4 + 1][j],
                                   v[q * 4 + 2][j], v[q * 4 + 3][j]) ^ 0x80808080u;
                lds[(pxg + j) * 66 + chg * 4 + h * 2 + q] = dw;
            }
    }
    __syncthreads();

    // ---- (a) xq store: 4 x v4i per thread, row-major coalesced ------------
    unsigned char* xqb = xq + ((size_t)b * HW + px0) * 256;
#pragma unroll
    for (int i = 0; i < 4; ++i) {
        int flat = tid + i * 256;
        int row = flat >> 4, off = (flat & 15) * 4;   // dword offset in row
        v4i o;
        o[0] = (int)lds[row * 66 + off + 0];
        o[1] = (int)lds[row * 66 + off + 1];
        o[2] = (int)lds[row * 66 + off + 2];
        o[3] = (int)lds[row * 66 + off + 3];
        *(v4i*)(xqb + (size_t)row * 256 + off * 4) = o;
    }

    // ---- (b) conv1 MFMA off the same LDS tile -----------------------------
    const int col = lane & 15, koff = lane >> 4;
    const int co0 = wv * 16;
    v4i acc[4];
#pragma unroll
    for (int i = 0; i < 4; ++i) acc[i] = (v4i){0, 0, 0, 0};

    const unsigned long long* ldsq = (const unsigned long long*)lds;
#pragma unroll
    for (int ks = 0; ks < 4; ++ks) {
#pragma unroll
        for (int nt = 0; nt < 4; ++nt) {
            int p = nt * 16 + col;
            int qi = p * 33 + ks * 8 + koff * 2;   // qword index (row = 33 qw)
            unsigned long long q0 = ldsq[qi];
            unsigned long long q1 = ldsq[qi + 1];
            v4i bf;
            bf[0] = (int)(unsigned)q0; bf[1] = (int)(q0 >> 32);
            bf[2] = (int)(unsigned)q1; bf[3] = (int)(q1 >> 32);
            acc[nt] = __builtin_amdgcn_mfma_i32_16x16x64_i8(a[ks], bf, acc[nt], 0, 0, 0);
        }
    }

    // ---- conv1+bn1 epilogue -> t1 -----------------------------------------
    const int zin = conv_zin[0];
    const int corr0 = 128 - zin;                   // acc was computed vs x-128
    const int cm0 = conv_m0[0], csh = conv_shift[0], czo = conv_zout[0];
    const int bm0 = bn_m0[0], bsh = bn_shift[0], bzo = bn_zout[0];
    const int zin2 = conv_zin[1];
    const long long cbv = 1LL << (30 + csh);
    const long long ccp = cbv + (1LL << 30), ccn = cbv + 1 - (1LL << 30);
    const int cshm1 = csh - 1;
    const long long bbv = 1LL << (30 + bsh);
    const long long bcp = bbv + (1LL << 30), bcn = bbv + 1 - (1LL << 30);
    const int bshm1 = bsh - 1;
    const int rowb = koff * 4;
    int bw[4], bbx[4], ws[4];
#pragma unroll
    for (int r = 0; r < 4; ++r) {
        bw[r] = (int)bn_w[co0 + rowb + r];
        bbx[r] = (int)bn_b[co0 + rowb + r] - czo * bw[r];
        ws[r] = wsum1[co0 + rowb + r];
    }
#pragma unroll
    for (int nt = 0; nt < 4; ++nt) {
        int n = b * HW + px0 + nt * 16 + col;
        int e[4];
#pragma unroll
        for (int r = 0; r < 4; ++r) {
            int av = acc[nt][r] + corr0 * ws[r];
            int qv = rq_apply(av, cm0, ccp, ccn, cshm1, czo);
            int a2 = qv * bw[r] + bbx[r];
            int q2 = rq_apply(a2, bm0, bcp, bcn, bshm1, bzo);
            e[r] = q2 - zin2;
        }
        *(unsigned*)(t1 + (size_t)n * 64 + co0 + rowb) = pk4x(e[0], e[1], e[2], e[3]);
    }
}

// -------- conv23: fused 3x3+bn2 (-> LDS) then 1x1 64->256 + bn3 + residual --
// grid (56, 32): 1 output row (64 px padded, 56 valid) x batch.
// Phase A: conv2 over 3 halo rows in sm -> t2s LDS (B-frag layout).
//          Residual xq dwords (all 4 steps) prefetched under phase-A epilogue.
// Phase B: bf[4] read once from t2s; 4 register-only MFMA+epilogue steps.
__global__ __launch_bounds__(256, 4) void k_conv23(
    const signed char* __restrict__ t1, const v4i* __restrict__ wp2,
    const v4i* __restrict__ wp3,
    const float* __restrict__ bn2_w, const float* __restrict__ bn2_b,
    const float* __restrict__ bn3_w, const float* __restrict__ bn3_b,
    const unsigned char* __restrict__ xq,
    const int* __restrict__ conv_zin, const int* __restrict__ conv_m0,
    const int* __restrict__ conv_shift, const int* __restrict__ conv_zout,
    const int* __restrict__ bn_m0, const int* __restrict__ bn_shift,
    const int* __restrict__ bn_zout,
    const int* __restrict__ add_z, const int* __restrict__ add_m0,
    const int* __restrict__ add_shift, const int* __restrict__ add_zout,
    int* __restrict__ out)
{
    __shared__ v4i sm[840];                       // 3 rows x 56 px x 80 B
    __shared__ v4i t2s[320];                      // 64 px x 80 B
    const int tid = threadIdx.x, lane = tid & 63, wv = tid >> 6;
    const int col = lane & 15, koff = lane >> 4;
    const int b = blockIdx.y;
    const int r0 = blockIdx.x;
    const int co0 = wv * 16, rowb = koff * 4;

    v4i a[9];
#pragma unroll
    for (int t = 0; t < 9; ++t) a[t] = wp2[(wv * 9 + t) * 64 + lane];
    v4i a3x[4];
#pragma unroll
    for (int s = 0; s < 4; ++s) a3x[s] = wp3[(wv * 4 + s) * 64 + lane];

    const v4i* t1v = (const v4i*)t1;
#pragma unroll
    for (int k = 0; k < 3; ++k) {
        int idx = tid + k * 256;
        if (idx < 672) {                          // 168 px x 4 parts
            int pixl = idx >> 2, part = idx & 3;
            int lrow = pixl / W56, gw = pixl - lrow * W56;
            int grow = r0 - 1 + lrow;
            v4i v = (v4i){0, 0, 0, 0};
            if ((unsigned)grow < 56u)
                v = t1v[((size_t)b * HW + grow * W56 + gw) * 4 + part];
            sm[pixl * 5 + part] = v;
        }
    }
    __syncthreads();

    v4i acc[4];
#pragma unroll
    for (int i = 0; i < 4; ++i) acc[i] = (v4i){0, 0, 0, 0};

#pragma unroll
    for (int kh = 0; kh < 3; ++kh) {
#pragma unroll
        for (int kw = 0; kw < 3; ++kw) {
            v4i af = a[kh * 3 + kw];
#pragma unroll
            for (int nt = 0; nt < 4; ++nt) {
                int sw = nt * 16 + col + kw - 1;
                bool valid = (unsigned)sw < 56u;
                v4i bf = sm[(kh * W56 + (valid ? sw : 0)) * 5 + koff];
                if (!valid) { bf[0] = 0; bf[1] = 0; bf[2] = 0; bf[3] = 0; }
                acc[nt] = __builtin_amdgcn_mfma_i32_16x16x64_i8(af, bf, acc[nt], 0, 0, 0);
            }
        }
    }

    // prefetch residual xq dwords for ALL 4 phase-B steps (16 VGPRs);
    // latency hides under the phase-A epilogue + barrier.
    int pxc[4];
#pragma unroll
    for (int nt = 0; nt < 4; ++nt) {
        int px = nt * 16 + col;
        pxc[nt] = px < 56 ? px : 55;
    }
    const unsigned char* xqb = xq + ((size_t)b * HW + r0 * W56) * 256 + wv * 64 + rowb;
    int xqv[4][4];                                // [t][nt]
#pragma unroll
    for (int t = 0; t < 4; ++t)
#pragma unroll
        for (int nt = 0; nt < 4; ++nt)
            xqv[t][nt] = *(const int*)(xqb + (size_t)pxc[nt] * 256 + t * 16);

    {   // phase A epilogue: requant + bn2, perm-pack -> t2s (B-frag layout)
        const int cm0 = conv_m0[1], csh = conv_shift[1], czo = conv_zout[1];
        const int bm0 = bn_m0[1], bsh = bn_shift[1], bzo = bn_zout[1];
        const int zin3 = conv_zin[2];
        const long long cbv = 1LL << (30 + csh);
        const long long ccp = cbv + (1LL << 30), ccn = cbv + 1 - (1LL << 30);
        const int cshm1 = csh - 1;
        const long long bbv = 1LL << (30 + bsh);
        const long long bcp = bbv + (1LL << 30), bcn = bbv + 1 - (1LL << 30);
        const int bshm1 = bsh - 1;
        int bw[4], bbx[4];
#pragma unroll
        for (int r = 0; r < 4; ++r) {
            bw[r] = (int)bn2_w[co0 + rowb + r];
            bbx[r] = (int)bn2_b[co0 + rowb + r] - czo * bw[r];
        }
#pragma unroll
        for (int nt = 0; nt < 4; ++nt) {
            int pix = nt * 16 + col;
            int e[4];
#pragma unroll
            for (int r = 0; r < 4; ++r) {
                int qv = rq_apply(acc[nt][r], cm0, ccp, ccn, cshm1, czo);
                int a2 = qv * bw[r] + bbx[r];
                int q2 = rq_apply(a2, bm0, bcp, bcn, bshm1, bzo);
                e[r] = q2 - zin3;
            }
            *(unsigned*)((char*)t2s + (size_t)(pix * 5 + wv) * 16 + koff * 4) =
                pk4x(e[0], e[1], e[2], e[3]);
        }
    }
    __syncthreads();                              // t2s ready

    // ---- phase B: 1x1 64->256 + bn3 + residual add (register-only loop) ----
    const int cm0 = conv_m0[2], csh = conv_shift[2], czo = conv_zout[2];
    const int bm0 = bn_m0[2], bsh = bn_shift[2], bzo = bn_zout[2];
    const long long cb3 = 1LL << (30 + csh);
    const long long ccp = cb3 + (1LL << 30), ccn = cb3 + 1 - (1LL << 30);
    const int cshm1 = csh - 1;
    const long long bb3 = 1LL << (30 + bsh);
    const long long bcp = bb3 + (1LL << 30), bcn = bb3 + 1 - (1LL << 30);
    const int bshm1 = bsh - 1;
    const int az0 = add_z[0], az1 = add_z[1];
    const int corr = 128 - az0;                   // xq holds x-128
    const int am0 = add_m0[0], am1 = add_m0[1];
    const int ash0 = add_shift[0], ash1 = add_shift[1];
    const long long a0b = 1LL << (30 + ash0);
    const long long acp0 = a0b + (1LL << 30), acn0 = a0b + 1 - (1LL << 30);
    const int ashm0 = ash0 - 1;
    const long long a1b = 1LL << (30 + ash1);
    const long long acp1 = a1b + (1LL << 30), acn1 = a1b + 1 - (1LL << 30);
    const int ashm1 = ash1 - 1;
    const int azout = add_zout[0];

    // bn3 params for all 4 steps (loads scheduled early in phase B)
    int bw3[4][4], bbx3[4][4];
#pragma unroll
    for (int s = 0; s < 4; ++s)
#pragma unroll
        for (int r = 0; r < 4; ++r) {
            bw3[s][r] = (int)bn3_w[wv * 64 + s * 16 + rowb + r];
            bbx3[s][r] = (int)bn3_b[wv * 64 + s * 16 + rowb + r] - czo * bw3[s][r];
        }

    v4i bf[4];                                    // t2s read ONCE
#pragma unroll
    for (int nt = 0; nt < 4; ++nt) bf[nt] = t2s[(nt * 16 + col) * 5 + koff];

    int* ob = out + (size_t)b * CIN * HW + (size_t)r0 * W56;

#pragma unroll
    for (int t = 0; t < 4; ++t) {
        const int c0 = wv * 64 + t * 16;
        v4i acc3[4];
#pragma unroll
        for (int i = 0; i < 4; ++i) acc3[i] = (v4i){0, 0, 0, 0};
#pragma unroll
        for (int nt = 0; nt < 4; ++nt)
            acc3[nt] = __builtin_amdgcn_mfma_i32_16x16x64_i8(a3x[t], bf[nt], acc3[nt], 0, 0, 0);
#pragma unroll
        for (int nt = 0; nt < 4; ++nt) {
            int px = nt * 16 + col;
            bool st = px < 56;
#pragma unroll
            for (int r = 0; r < 4; ++r) {
                int sx = (int)(signed char)(((unsigned)xqv[t][nt]) >> (8 * r));
                int qv = rq_apply(acc3[nt][r], cm0, ccp, ccn, cshm1, czo);
                int a2 = qv * bw3[t][r] + bbx3[t][r];
                int q2 = rq_apply(a2, bm0, bcp, bcn, bshm1, bzo);
                int ra = ms_apply(sx + corr, am0, acp0, acn0, ashm0);
                int rb = ms_apply(q2 - az1, am1, acp1, acn1, ashm1);
                int res = ra + rb + azout;
                res = res < 0 ? 0 : (res > 255 ? 255 : res);
                if (st) ob[(size_t)(c0 + rowb + r) * HW + px] = res;
            }
        }
    }
}

extern "C" void kernel_launch(void* const* d_in, const int* in_sizes, int n_in,
                              void* d_out, int out_size, void* d_ws, size_t ws_size,
                              hipStream_t stream) {
    const int* x = (const int*)d_in[0];
    const float* w1 = (const float*)d_in[1];
    const float* w2 = (const float*)d_in[2];
    const float* w3 = (const float*)d_in[3];
    const float* bn1_w = (const float*)d_in[4];
    const float* bn1_b = (const float*)d_in[5];
    const float* bn2_w = (const float*)d_in[6];
    const float* bn2_b = (const float*)d_in[7];
    const float* bn3_w = (const float*)d_in[8];
    const float* bn3_b = (const float*)d_in[9];
    const int* conv_zin = (const int*)d_in[10];
    const int* conv_m0 = (const int*)d_in[11];
    const int* conv_shift = (const int*)d_in[12];
    const int* conv_zout = (const int*)d_in[13];
    const int* bn_m0 = (const int*)d_in[14];
    const int* bn_shift = (const int*)d_in[15];
    const int* bn_zout = (const int*)d_in[16];
    const int* add_z = (const int*)d_in[17];
    const int* add_m0 = (const int*)d_in[18];
    const int* add_shift = (const int*)d_in[19];
    const int* add_zout = (const int*)d_in[20];

    v4i* wp = (v4i*)d_ws;
    int* wsum1 = (int*)((char*)d_ws + WP_BYTES);
    signed char* t1 = (signed char*)d_ws + WP_BYTES + WSUM_BYTES;
    unsigned char* xq = (unsigned char*)t1 + T1_BYTES;

    const v4i* wp1 = wp;
    const v4i* wp2 = wp + 16 * 64;
    const v4i* wp3 = wp + 52 * 64;

    k_prep<<<dim3(18), dim3(256), 0, stream>>>(w1, w2, w3, wp, wsum1);
    k_pack1<<<dim3(49, 32), dim3(256), 0, stream>>>(x, wp1, wsum1, bn1_w, bn1_b,
        conv_zin, conv_m0, conv_shift, conv_zout, bn_m0, bn_shift, bn_zout, t1, xq);
    k_conv23<<<dim3(56, 32), dim3(256), 0, stream>>>(t1, wp2, wp3,
        bn2_w, bn2_b, bn3_w, bn3_b, xq,
        conv_zin, conv_m0, conv_shift, conv_zout, bn_m0, bn_shift, bn_zout,
        add_z, add_m0, add_shift, add_zout, (int*)d_out);
}